// Round 10
// baseline (153.432 us; speedup 1.0000x reference)
//
#include <hip/hip_runtime.h>
#include <cstddef>

typedef float  f32x4  __attribute__((ext_vector_type(4)));
typedef __bf16 bf16x8 __attribute__((ext_vector_type(8)));
typedef __bf16 bf16x4 __attribute__((ext_vector_type(4)));

#define DEV static __device__ __forceinline__

DEV float sigf(float x){ return 1.f/(1.f+__expf(-x)); }
DEV float tanh_f(float x){
  x = fminf(fmaxf(x, -20.f), 20.f);
  float e = __expf(2.f*x);
  return (e-1.f)/(e+1.f);
}

DEV bf16x8 cvt8(const float4 a, const float4 b){
  bf16x8 r;
  r[0]=(__bf16)a.x; r[1]=(__bf16)a.y; r[2]=(__bf16)a.z; r[3]=(__bf16)a.w;
  r[4]=(__bf16)b.x; r[5]=(__bf16)b.y; r[6]=(__bf16)b.z; r[7]=(__bf16)b.w;
  return r;
}

// async global -> LDS: per-lane global src (lane l reads its own 16B),
// wave-uniform LDS dst (lane l lands at dst + l*16B)
typedef const __attribute__((address_space(1))) unsigned int* gas_t;
typedef __attribute__((address_space(3))) unsigned int* las_t;
DEV void gll16(const void* g, void* l){
  __builtin_amdgcn_global_load_lds((gas_t)g, (las_t)l, 16, 0, 0);
}

// ---------------- fragment-layout convert: f32 row-major -> bf16 MFMA tiles ------
// src: [nTiles][16 rows][512 cols] f32. Tile (gt,sub): lane l holds
// src[gt*16 + (l&15)][sub*32 + (l>>4)*8 .. +8] at dst[(gt*16+sub)*512 + l*8].
// Contiguous 1 KB per tile -> single coalesced load in consumers.
__global__ void k_frag(const float* __restrict__ src, __bf16* __restrict__ dst)
{
  const int idx = blockIdx.x*256 + threadIdx.x;
  const int l   = idx & 63;
  const int sub = (idx >> 6) & 15;
  const int gt  = idx >> 10;
  const float* p = src + ((size_t)gt*16 + (l&15))*512 + sub*32 + (l>>4)*8;
  float4 v0 = *(const float4*)p;
  float4 v1 = *(const float4*)(p+4);
  *(bf16x8*)(dst + ((size_t)(gt*16 + sub)*64 + l)*8) = cvt8(v0, v1);
}

// ---------------- ph = h_last @ W_ph^T : (128,256) ----------------
__global__ void k_ph(const float* __restrict__ h0, const float* __restrict__ W_ph,
                     float* __restrict__ ph)
{
  const int b = blockIdx.x, a = threadIdx.x;
  __shared__ float h_s[1024];
  for (int k = a; k < 1024; k += 256) h_s[k] = h0[(size_t)b*1024 + k];
  __syncthreads();
  const float* wr = W_ph + (size_t)a*1024;
  float acc = 0.f;
  for (int k = 0; k < 1024; k += 4){
    float4 w = *(const float4*)(wr + k);
    acc += w.x*h_s[k] + w.y*h_s[k+1] + w.z*h_s[k+2] + w.w*h_s[k+3];
  }
  ph[b*256 + a] = acc;
}

// ---------------- xh[:,0:512]=embed, xh[:,1024:2048]=h0 ----------------
__global__ void k_concat(const float* __restrict__ embed, const float* __restrict__ h0,
                         float* __restrict__ xh)
{
  const int b = blockIdx.x, tid = threadIdx.x;
  *(float2*)(xh + (size_t)b*2048 + tid*2) = *(const float2*)(embed + (size_t)b*512 + tid*2);
  *(float4*)(xh + (size_t)b*2048 + 1024 + tid*4) = *(const float4*)(h0 + (size_t)b*1024 + tid*4);
}

// ---------------- scores: both operands bf16 fragment layout, async gload_lds ----
// block: 256 t x 256 a, 512 threads (8 waves x 32 t), K=512 in 16 kt (4 quarters).
// A: encX tiles, 2 contiguous 1KB gll16/kt/wave, wave-private dbuf, counted vmcnt.
// B: wpeX quarter (64 chunks, 64 KB) LDS-resident, restaged 4x, 2 barriers/quarter.
__global__ __launch_bounds__(512,1) void k_scores(
    const __bf16* __restrict__ encX, const __bf16* __restrict__ wpeX,
    const float* __restrict__ ph, const float* __restrict__ w_fc2,
    float* __restrict__ scores)
{
  const int b  = blockIdx.y;
  const int tc = blockIdx.x;            // t-chunk of 256
  const int tid = threadIdx.x;
  const int w = tid >> 6, l = tid & 63;
  const int la = l & 15, g = l >> 4;

  __shared__ __align__(16) __bf16 A_s[2*8*2*512];  // 32 KB: ((buf*8+w)*2+tt)*512
  __shared__ __align__(16) __bf16 B_s[64*512];     // 64 KB: chunk (nf*4+ktl)*512
  __shared__ float ph_s[256], w2_s[256];
  if (tid < 256){ ph_s[tid] = ph[b*256 + tid]; w2_s[tid] = w_fc2[tid]; }

  // wave's A row-tiles: gt0 = b*32 + tc*16 + w*2 (tiles gt0, gt0+1)
  const __bf16* aglX = encX + ((size_t)(b*32 + tc*16 + w*2)*16)*512 + l*8;

  f32x4 acc[2][16];
  #pragma unroll
  for (int i = 0; i < 2; ++i)
    #pragma unroll
    for (int j = 0; j < 16; ++j) acc[i][j] = (f32x4){0.f,0.f,0.f,0.f};

#define ISSUE_A(KT, BUF) {                                                    \
    const __bf16* s_ = aglX + (size_t)(KT)*512;                               \
    __bf16* d_ = A_s + (((BUF)*8 + w)*2)*512;                                 \
    gll16(s_,            d_);        /* tile tt0, kt */                       \
    gll16(s_ + 16*512,   d_ + 512);  /* tile tt1, kt */                       \
  }

// stage B quarter Q: 64 chunks (nf*4+ktl); wave w stages chunks w*8..w*8+7.
#define ISSUE_B(Q)                                                            \
  _Pragma("unroll")                                                           \
  for (int i = 0; i < 8; ++i){                                                \
    const int c_ = w*8 + i;                                                   \
    const int nf_ = c_ >> 2, ktl_ = c_ & 3;                                   \
    gll16(wpeX + (size_t)(nf_*16 + (Q)*4 + ktl_)*512 + l*8,                   \
          B_s + (size_t)c_*512);                                              \
  }

#define WAIT2 { asm volatile("s_waitcnt vmcnt(2)" ::: "memory");              \
                __builtin_amdgcn_sched_barrier(0); }
#define WAIT0 { asm volatile("s_waitcnt vmcnt(0)" ::: "memory");              \
                __builtin_amdgcn_sched_barrier(0); }

#define CONSUME(BUF, KTL) {                                                   \
    const __bf16* ab = A_s + (((BUF)*8 + w)*2)*512 + l*8;                     \
    bf16x8 af0 = *(const bf16x8*)(ab);                                        \
    bf16x8 af1 = *(const bf16x8*)(ab + 512);                                  \
    _Pragma("unroll")                                                         \
    for (int nf = 0; nf < 16; ++nf){                                          \
      bf16x8 bf = *(const bf16x8*)(B_s + (size_t)(nf*4 + (KTL))*512 + l*8);   \
      acc[0][nf] = __builtin_amdgcn_mfma_f32_16x16x32_bf16(af0, bf, acc[0][nf], 0,0,0); \
      acc[1][nf] = __builtin_amdgcn_mfma_f32_16x16x32_bf16(af1, bf, acc[1][nf], 0,0,0); \
    } }

// one quarter: 4 kt pipelined (A dbuf, counted waits), then restage B
#define QUARTER(K0)                                                           \
  ISSUE_A((K0)+1,1) WAIT2 CONSUME(0,0)                                        \
  ISSUE_A((K0)+2,0) WAIT2 CONSUME(1,1)                                        \
  ISSUE_A((K0)+3,1) WAIT2 CONSUME(0,2)                                        \
  WAIT0 CONSUME(1,3)

#define RESTAGE(QN, KN)                                                       \
  ISSUE_A(KN,0)                  /* prefetch next quarter's first A */        \
  __syncthreads();               /* all waves done reading B quarter */       \
  ISSUE_B(QN)                                                                 \
  WAIT0                          /* drain B (and A KN) */                     \
  __syncthreads();               /* B quarter visible to all waves */

  // prologue
  ISSUE_B(0)
  ISSUE_A(0,0)
  WAIT0
  __syncthreads();

  QUARTER(0)
  RESTAGE(1, 4)
  QUARTER(4)
  RESTAGE(2, 8)
  QUARTER(8)
  RESTAGE(3, 12)
  QUARTER(12)

#undef ISSUE_A
#undef ISSUE_B
#undef WAIT2
#undef WAIT0
#undef CONSUME
#undef QUARTER
#undef RESTAGE

  // epilogue: s[t] = sum_a tanh(pe + ph[a]) * w2[a]; D: row=g*4+r, col=la
  #pragma unroll
  for (int mfi = 0; mfi < 2; ++mfi){
    #pragma unroll
    for (int r = 0; r < 4; ++r){
      float s = 0.f;
      #pragma unroll
      for (int nf = 0; nf < 16; ++nf){
        float v = acc[mfi][nf][r] + ph_s[nf*16 + la];
        s += tanh_f(v) * w2_s[nf*16 + la];
      }
      s += __shfl_xor(s, 1, 16);
      s += __shfl_xor(s, 2, 16);
      s += __shfl_xor(s, 4, 16);
      s += __shfl_xor(s, 8, 16);
      if (la == 0){
        int t = tc*256 + w*32 + mfi*16 + g*4 + r;
        scores[b*512 + t] = s;
      }
    }
  }
}

// ---------------- softmax over T=512 per batch row (in-place ok) ----------------
__global__ void k_softmax(const float* __restrict__ scores, const unsigned char* __restrict__ mask,
                          float* __restrict__ aw)
{
  const int b = blockIdx.x, tid = threadIdx.x;
  float s0 = scores[b*512 + tid];
  float s1 = scores[b*512 + 256 + tid];
  if (mask[b*512 + tid])       s0 = -1e30f;
  if (mask[b*512 + 256 + tid]) s1 = -1e30f;
  float m = fmaxf(s0, s1);
  #pragma unroll
  for (int o = 32; o; o >>= 1) m = fmaxf(m, __shfl_xor(m, o, 64));
  __shared__ float redm[4], reds[4];
  const int wv = tid >> 6, lx = tid & 63;
  if (lx == 0) redm[wv] = m;
  __syncthreads();
  m = fmaxf(fmaxf(redm[0], redm[1]), fmaxf(redm[2], redm[3]));
  float e0 = __expf(s0 - m), e1 = __expf(s1 - m);
  float ss = e0 + e1;
  #pragma unroll
  for (int o = 32; o; o >>= 1) ss += __shfl_xor(ss, o, 64);
  if (lx == 0) reds[wv] = ss;
  __syncthreads();
  ss = reds[0] + reds[1] + reds[2] + reds[3];
  float inv = 1.f / ss;
  aw[b*512 + tid]       = e0 * inv;
  aw[b*512 + 256 + tid] = e1 * inv;
}

// ---------------- ctxt partials: grid (128 b, 8 q), 64 t/block, 8-deep MLP -------
__global__ void k_ctxt(const float* __restrict__ enc, const float* __restrict__ aw,
                       float* __restrict__ part)
{
  const int b = blockIdx.x, q = blockIdx.y, tid = threadIdx.x;
  const int tr = tid >> 7, ec = tid & 127;
  __shared__ float aw_s[64];
  if (tid < 64) aw_s[tid] = aw[b*512 + q*64 + tid];
  __syncthreads();
  const float* ep = enc + ((size_t)b*512 + q*64 + tr*32)*512 + ec*4;
  f32x4 s0 = {0.f,0.f,0.f,0.f}, s1 = s0, s2 = s0, s3 = s0;
  f32x4 s4 = s0, s5 = s0, s6 = s0, s7 = s0;
  #pragma unroll
  for (int t = 0; t < 32; t += 8){
    f32x4 e0 = *(const f32x4*)(ep + (size_t)(t  )*512);
    f32x4 e1 = *(const f32x4*)(ep + (size_t)(t+1)*512);
    f32x4 e2 = *(const f32x4*)(ep + (size_t)(t+2)*512);
    f32x4 e3 = *(const f32x4*)(ep + (size_t)(t+3)*512);
    f32x4 e4 = *(const f32x4*)(ep + (size_t)(t+4)*512);
    f32x4 e5 = *(const f32x4*)(ep + (size_t)(t+5)*512);
    f32x4 e6 = *(const f32x4*)(ep + (size_t)(t+6)*512);
    f32x4 e7 = *(const f32x4*)(ep + (size_t)(t+7)*512);
    const float* awp = aw_s + tr*32 + t;
    s0 += e0 * awp[0]; s1 += e1 * awp[1]; s2 += e2 * awp[2]; s3 += e3 * awp[3];
    s4 += e4 * awp[4]; s5 += e5 * awp[5]; s6 += e6 * awp[6]; s7 += e7 * awp[7];
  }
  f32x4 s = ((s0+s1)+(s2+s3)) + ((s4+s5)+(s6+s7));
  __shared__ f32x4 red[128];
  if (tr == 1) red[ec] = s;
  __syncthreads();
  if (tr == 0){
    s += red[ec];
    *(f32x4*)(part + ((size_t)q*128 + b)*512 + ec*4) = s;
  }
}

// ---------------- finalize ctxt -> xh[:,512:1024], hc[:,1024:1536] ----------------
__global__ void k_ctxt_fin(const float* __restrict__ part, float* __restrict__ xh,
                           float* __restrict__ hc)
{
  const int b = blockIdx.x, tid = threadIdx.x;
  const int e = tid*2;
  float sx = 0.f, sy = 0.f;
  #pragma unroll
  for (int q = 0; q < 8; ++q){
    float2 p = *(const float2*)(part + ((size_t)q*128 + b)*512 + e);
    sx += p.x; sy += p.y;
  }
  float2 r; r.x = sx; r.y = sy;
  *(float2*)(xh + (size_t)b*2048 + 512 + e) = r;
  *(float2*)(hc + (size_t)b*1536 + 1024 + e) = r;
}

// ---------------- partial GEMM: Cpart[kc][128][N] = A[:,koff:koff+Kloc] @ W^T ------
__global__ __launch_bounds__(256,2) void k_gemm_part(
    const float* __restrict__ A, int lda,
    const float* __restrict__ W1, int ldw1,
    const float* __restrict__ W2, int ldw2, int ksplit,
    float* __restrict__ Cpart, int ldc, int Kloc)
{
  const int jt = blockIdx.x * 32;
  const int kc = blockIdx.y;
  const int koff = kc * Kloc;
  const int tid = threadIdx.x;
  const int w = tid >> 6, lane = tid & 63;
  const int la = lane & 15, g = lane >> 4;

  __shared__ __align__(16) __bf16 A_s[128][40];
  __shared__ __align__(16) __bf16 B_s[32][40];

  f32x4 acc[2][2];
  #pragma unroll
  for (int i = 0; i < 2; ++i)
    #pragma unroll
    for (int j = 0; j < 2; ++j) acc[i][j] = (f32x4){0.f,0.f,0.f,0.f};

  const int ar = tid >> 1, ac = (tid & 1) * 16;
  const int br = tid >> 3, bc = (tid & 7) * 4;

  for (int kl = 0; kl < Kloc; kl += 32){
    const int kk = koff + kl;
    {
      const float* p = A + (size_t)ar*lda + kk + ac;
      float4 v0 = *(const float4*)(p);
      float4 v1 = *(const float4*)(p+4);
      float4 v2 = *(const float4*)(p+8);
      float4 v3 = *(const float4*)(p+12);
      *(bf16x8*)&A_s[ar][ac]   = cvt8(v0,v1);
      *(bf16x8*)&A_s[ar][ac+8] = cvt8(v2,v3);
    }
    {
      const float* wp = (kk < ksplit)
          ? (W1 + (size_t)(jt+br)*ldw1 + kk + bc)
          : (W2 + (size_t)(jt+br)*ldw2 + (kk - ksplit) + bc);
      float4 v = *(const float4*)wp;
      bf16x4 bv;
      bv[0]=(__bf16)v.x; bv[1]=(__bf16)v.y; bv[2]=(__bf16)v.z; bv[3]=(__bf16)v.w;
      *(bf16x4*)&B_s[br][bc] = bv;
    }
    __syncthreads();
    bf16x8 a0 = *(const bf16x8*)&A_s[w*32 + la][g*8];
    bf16x8 a1 = *(const bf16x8*)&A_s[w*32 + 16 + la][g*8];
    bf16x8 b0 = *(const bf16x8*)&B_s[la][g*8];
    bf16x8 b1 = *(const bf16x8*)&B_s[16 + la][g*8];
    acc[0][0] = __builtin_amdgcn_mfma_f32_16x16x32_bf16(a0, b0, acc[0][0], 0,0,0);
    acc[0][1] = __builtin_amdgcn_mfma_f32_16x16x32_bf16(a0, b1, acc[0][1], 0,0,0);
    acc[1][0] = __builtin_amdgcn_mfma_f32_16x16x32_bf16(a1, b0, acc[1][0], 0,0,0);
    acc[1][1] = __builtin_amdgcn_mfma_f32_16x16x32_bf16(a1, b1, acc[1][1], 0,0,0);
    __syncthreads();
  }

  float* cp = Cpart + (size_t)kc*128*ldc;
  #pragma unroll
  for (int mfi = 0; mfi < 2; ++mfi)
    #pragma unroll
    for (int nf = 0; nf < 2; ++nf)
      #pragma unroll
      for (int r = 0; r < 4; ++r){
        int m = w*32 + mfi*16 + g*4 + r;
        int j = jt + nf*16 + la;
        cp[(size_t)m*ldc + j] = acc[mfi][nf][r];
      }
}

// ---------------- LSTM finisher: sum 4 partials + biases + pointwise ----------------
__global__ void k_lstm_fin(const float* __restrict__ partG, const float* __restrict__ b_ih,
                           const float* __restrict__ b_hh, const float* __restrict__ c0,
                           float* __restrict__ out, float* __restrict__ hc)
{
  const int idx = blockIdx.x*256 + threadIdx.x;   // 0..131071
  const int b = idx >> 10, h = idx & 1023;
  float gi = b_ih[h]        + b_hh[h];
  float gf = b_ih[1024 + h] + b_hh[1024 + h];
  float gg = b_ih[2048 + h] + b_hh[2048 + h];
  float go = b_ih[3072 + h] + b_hh[3072 + h];
  #pragma unroll
  for (int kc = 0; kc < 4; ++kc){
    const float* gp = partG + ((size_t)kc*128 + b)*4096;
    gi += gp[h]; gf += gp[1024 + h]; gg += gp[2048 + h]; go += gp[3072 + h];
  }
  float c1 = sigf(gf)*c0[idx] + sigf(gi)*tanh_f(gg);
  float h1 = sigf(go)*tanh_f(c1);
  out[131072 + idx] = h1;
  out[262144 + idx] = c1;
  hc[(size_t)b*1536 + h] = h1;
}

// ---------------- proj finisher: sum 4 partials + bias + tanh -> out[:131072] ------
__global__ void k_proj_fin(const float* __restrict__ partP, const float* __restrict__ b_proj,
                           float* __restrict__ out)
{
  const int idx = blockIdx.x*256 + threadIdx.x;   // 0..131071
  const int b = idx >> 10, j = idx & 1023;
  float s = b_proj[j];
  #pragma unroll
  for (int kc = 0; kc < 4; ++kc)
    s += partP[((size_t)kc*128 + b)*1024 + j];
  out[idx] = tanh_f(s);
}

extern "C" void kernel_launch(void* const* d_in, const int* in_sizes, int n_in,
                              void* d_out, int out_size, void* d_ws, size_t ws_size,
                              hipStream_t stream)
{
  const float* embed  = (const float*)d_in[0];
  const float* h0     = (const float*)d_in[1];
  const float* c0     = (const float*)d_in[2];
  const float* enc    = (const float*)d_in[3];
  const float* W_ph   = (const float*)d_in[4];
  const float* W_pe   = (const float*)d_in[5];
  const float* w_fc2  = (const float*)d_in[6];
  const float* W_ih   = (const float*)d_in[7];
  const float* W_hh   = (const float*)d_in[8];
  const float* b_ih   = (const float*)d_in[9];
  const float* b_hh   = (const float*)d_in[10];
  const float* W_proj = (const float*)d_in[11];
  const float* b_proj = (const float*)d_in[12];
  const unsigned char* mask = (const unsigned char*)d_in[13];

  float* ws     = (float*)d_ws;
  float* ph     = ws;                   //   32768
  float* scores = ws + 32768;           //   65536 (aw in place)
  float* xh     = ws + 98304;           //  262144 (128x2048: [embed|ctxt|h])
  float* hc     = ws + 360448;          //  196608 (128x1536: [h1|ctxt])
  float* partG  = ws + 557056;          // 2097152 (4 x 128 x 4096); first 8x128x512
                                        //   reused as ctxt partials (disjoint lifetime)
  float* part   = partG;
  float* partP  = ws + 2654208;         //  524288 (4 x 128 x 1024)
  __bf16* wpeX  = (__bf16*)(ws + 3178496);      //     131072 bf16 (256 KB)
  __bf16* encX  = (__bf16*)(ws + 3244032);      // 33,554,432 bf16 (64 MB)
  float* out    = (float*)d_out;

  k_frag   <<<16384, 256, 0, stream>>>(enc, encX);   // 4096 row-tiles
  k_frag   <<<64, 256, 0, stream>>>(W_pe, wpeX);     //   16 row-tiles
  k_ph     <<<128, 256, 0, stream>>>(h0, W_ph, ph);
  k_concat <<<128, 256, 0, stream>>>(embed, h0, xh);
  k_scores <<<dim3(2,128), 512, 0, stream>>>(encX, wpeX, ph, w_fc2, scores);
  k_softmax<<<128, 256, 0, stream>>>(scores, mask, scores);
  k_ctxt   <<<dim3(128,8), 256, 0, stream>>>(enc, scores, part);
  k_ctxt_fin<<<128, 256, 0, stream>>>(part, xh, hc);
  k_gemm_part<<<dim3(128,4), 256, 0, stream>>>(xh, 2048, W_ih, 1024, W_hh, 1024, 1024,
                                               partG, 4096, 512);
  k_lstm_fin<<<512, 256, 0, stream>>>(partG, b_ih, b_hh, c0, out, hc);
  k_gemm_part<<<dim3(32,4), 256, 0, stream>>>(hc, 1536, W_proj, 1536, nullptr, 0, 1536,
                                              partP, 1024, 384);
  k_proj_fin<<<512, 256, 0, stream>>>(partP, b_proj, out);
}

// Round 11
// 117.749 us; speedup vs baseline: 1.3030x; 1.3030x over previous
//
#include <hip/hip_runtime.h>
#include <cstddef>

typedef float  f32x4  __attribute__((ext_vector_type(4)));
typedef __bf16 bf16x8 __attribute__((ext_vector_type(8)));
typedef __bf16 bf16x4 __attribute__((ext_vector_type(4)));

#define DEV static __device__ __forceinline__

DEV float sigf(float x){ return 1.f/(1.f+__expf(-x)); }
DEV float tanh_f(float x){
  x = fminf(fmaxf(x, -20.f), 20.f);
  float e = __expf(2.f*x);
  return (e-1.f)/(e+1.f);
}

DEV bf16x8 cvt8(const float4 a, const float4 b){
  bf16x8 r;
  r[0]=(__bf16)a.x; r[1]=(__bf16)a.y; r[2]=(__bf16)a.z; r[3]=(__bf16)a.w;
  r[4]=(__bf16)b.x; r[5]=(__bf16)b.y; r[6]=(__bf16)b.z; r[7]=(__bf16)b.w;
  return r;
}

// ---------------- fragment-layout convert (W_pe only): f32 -> bf16 MFMA tiles ----
// lane l of tile (gt,sub) holds src[gt*16 + (l&15)][sub*32 + (l>>4)*8 .. +8]
__global__ void k_frag(const float* __restrict__ src, __bf16* __restrict__ dst)
{
  const int idx = blockIdx.x*256 + threadIdx.x;
  const int l   = idx & 63;
  const int sub = (idx >> 6) & 15;
  const int gt  = idx >> 10;
  const float* p = src + ((size_t)gt*16 + (l&15))*512 + sub*32 + (l>>4)*8;
  float4 v0 = *(const float4*)p;
  float4 v1 = *(const float4*)(p+4);
  *(bf16x8*)(dst + ((size_t)(gt*16 + sub)*64 + l)*8) = cvt8(v0, v1);
}

// ---------------- ph = h_last @ W_ph^T : (128,256) ----------------
__global__ void k_ph(const float* __restrict__ h0, const float* __restrict__ W_ph,
                     float* __restrict__ ph)
{
  const int b = blockIdx.x, a = threadIdx.x;
  __shared__ float h_s[1024];
  for (int k = a; k < 1024; k += 256) h_s[k] = h0[(size_t)b*1024 + k];
  __syncthreads();
  const float* wr = W_ph + (size_t)a*1024;
  float acc = 0.f;
  for (int k = 0; k < 1024; k += 4){
    float4 w = *(const float4*)(wr + k);
    acc += w.x*h_s[k] + w.y*h_s[k+1] + w.z*h_s[k+2] + w.w*h_s[k+3];
  }
  ph[b*256 + a] = acc;
}

// ---------------- xh[:,0:512]=embed, xh[:,1024:2048]=h0 ----------------
__global__ void k_concat(const float* __restrict__ embed, const float* __restrict__ h0,
                         float* __restrict__ xh)
{
  const int b = blockIdx.x, tid = threadIdx.x;
  *(float2*)(xh + (size_t)b*2048 + tid*2) = *(const float2*)(embed + (size_t)b*512 + tid*2);
  *(float4*)(xh + (size_t)b*2048 + 1024 + tid*4) = *(const float4*)(h0 + (size_t)b*1024 + tid*4);
}

// ---------------- fused scores+softmax+ctxt (flash-style, online softmax) --------
// grid (2 t-halves, 128 b) x 512 threads (8 waves). Per block: 256 t rows.
// enc tile (32 t x 512 K) staged ONCE per tile into LDS bf16 row-major [32][520];
// used by QK (MFMA A-frags) and PV (weighted sum). W_pe frags live in VGPRs.
#define RMW 520
__global__ __launch_bounds__(512,1) void k_fused(
    const float* __restrict__ enc, const __bf16* __restrict__ wpeX,
    const float* __restrict__ ph, const float* __restrict__ w_fc2,
    const unsigned char* __restrict__ mask,
    float* __restrict__ partC, float* __restrict__ partML)
{
  const int th = blockIdx.x;          // t-half
  const int b  = blockIdx.y;
  const int tid = threadIdx.x;
  const int w = tid >> 6, l = tid & 63;
  const int la = l & 15, g = l >> 4;

  __shared__ __align__(16) __bf16 rm[2][32*RMW];
  __shared__ float sred[8][32];
  __shared__ float p_s[32];
  __shared__ float ph_s[256], w2_s[256];
  __shared__ float stM, stL, rsS;

  if (tid < 256){ ph_s[tid] = ph[b*256 + tid]; w2_s[tid] = w_fc2[tid]; }
  if (tid == 0){ stM = -1e30f; stL = 0.f; }

  // W_pe fragments in registers: wave w owns a-tiles w*2 (cols w*32..+15)
  // and w*2+1 (cols w*32+16..+31); 16 kt each.
  bf16x8 Bf0[16], Bf1[16];
  {
    const __bf16* bp0 = wpeX + ((size_t)(w*2    )*16*64 + l)*8;
    const __bf16* bp1 = wpeX + ((size_t)(w*2 + 1)*16*64 + l)*8;
    #pragma unroll
    for (int kt = 0; kt < 16; ++kt){
      Bf0[kt] = *(const bf16x8*)(bp0 + (size_t)kt*512);
      Bf1[kt] = *(const bf16x8*)(bp1 + (size_t)kt*512);
    }
  }

  const int t0 = th*256;
  const int srow = tid >> 7;               // 0..3 (row group)
  const int scol = (tid & 127) * 4;        // 0..508
  const float* gsrc = enc + ((size_t)b*512 + t0 + srow)*512 + scol;

  float4 st[8];
  // prologue: stage tile 0 (rows srow+rr*4, cols scol..scol+3)
  #pragma unroll
  for (int rr = 0; rr < 8; ++rr)
    st[rr] = *(const float4*)(gsrc + (size_t)rr*4*512);
  #pragma unroll
  for (int rr = 0; rr < 8; ++rr){
    float4 v = st[rr];
    bf16x4 bv; bv[0]=(__bf16)v.x; bv[1]=(__bf16)v.y; bv[2]=(__bf16)v.z; bv[3]=(__bf16)v.w;
    *(bf16x4*)&rm[0][(srow + rr*4)*RMW + scol] = bv;
  }
  __syncthreads();

  float cacc = 0.f;

  for (int tile = 0; tile < 8; ++tile){
    const int cur = tile & 1;
    // issue next tile's global loads early (arrive under QK compute)
    if (tile < 7){
      const float* gn = gsrc + (size_t)(tile+1)*32*512;
      #pragma unroll
      for (int rr = 0; rr < 8; ++rr)
        st[rr] = *(const float4*)(gn + (size_t)rr*4*512);
    }
    // QK: pe tile (32t x 32a per wave), K=512
    f32x4 acc00 = {0.f,0.f,0.f,0.f}, acc01 = acc00, acc10 = acc00, acc11 = acc00;
    const __bf16* rb = &rm[cur][0];
    #pragma unroll
    for (int kt = 0; kt < 16; ++kt){
      bf16x8 a0 = *(const bf16x8*)(rb + (la     )*RMW + kt*32 + g*8);
      bf16x8 a1 = *(const bf16x8*)(rb + (16 + la)*RMW + kt*32 + g*8);
      acc00 = __builtin_amdgcn_mfma_f32_16x16x32_bf16(a0, Bf0[kt], acc00, 0,0,0);
      acc01 = __builtin_amdgcn_mfma_f32_16x16x32_bf16(a0, Bf1[kt], acc01, 0,0,0);
      acc10 = __builtin_amdgcn_mfma_f32_16x16x32_bf16(a1, Bf0[kt], acc10, 0,0,0);
      acc11 = __builtin_amdgcn_mfma_f32_16x16x32_bf16(a1, Bf1[kt], acc11, 0,0,0);
    }
    // epilogue: partial score over wave's 32 a-cols; D: row=g*4+r, col=la
    {
      const float phv0 = ph_s[w*32 + la],      w2v0 = w2_s[w*32 + la];
      const float phv1 = ph_s[w*32 + 16 + la], w2v1 = w2_s[w*32 + 16 + la];
      #pragma unroll
      for (int gt = 0; gt < 2; ++gt){
        const f32x4 pa = gt ? acc10 : acc00;
        const f32x4 pb = gt ? acc11 : acc01;
        #pragma unroll
        for (int r = 0; r < 4; ++r){
          float s = tanh_f(pa[r] + phv0)*w2v0 + tanh_f(pb[r] + phv1)*w2v1;
          s += __shfl_xor(s, 1, 16);
          s += __shfl_xor(s, 2, 16);
          s += __shfl_xor(s, 4, 16);
          s += __shfl_xor(s, 8, 16);
          if (la == 0) sred[w][gt*16 + g*4 + r] = s;
        }
      }
    }
    // stage-write next tile (loads already in flight)
    if (tile < 7){
      #pragma unroll
      for (int rr = 0; rr < 8; ++rr){
        float4 v = st[rr];
        bf16x4 bv; bv[0]=(__bf16)v.x; bv[1]=(__bf16)v.y; bv[2]=(__bf16)v.z; bv[3]=(__bf16)v.w;
        *(bf16x4*)&rm[cur^1][(srow + rr*4)*RMW + scol] = bv;
      }
    }
    __syncthreads();
    // softmax state update (one half-wave)
    if (tid < 32){
      const int t = tid;
      float s = sred[0][t]+sred[1][t]+sred[2][t]+sred[3][t]
              + sred[4][t]+sred[5][t]+sred[6][t]+sred[7][t];
      const bool mk = mask[b*512 + t0 + tile*32 + t] != 0;
      if (mk) s = -1e30f;
      float mold = stM;
      float mx = s;
      mx = fmaxf(mx, __shfl_xor(mx, 1, 32));
      mx = fmaxf(mx, __shfl_xor(mx, 2, 32));
      mx = fmaxf(mx, __shfl_xor(mx, 4, 32));
      mx = fmaxf(mx, __shfl_xor(mx, 8, 32));
      mx = fmaxf(mx, __shfl_xor(mx, 16, 32));
      float mnew = fmaxf(mold, mx);
      float p = mk ? 0.f : __expf(s - mnew);
      p_s[t] = p;
      float lt = p;
      lt += __shfl_xor(lt, 1, 32);
      lt += __shfl_xor(lt, 2, 32);
      lt += __shfl_xor(lt, 4, 32);
      lt += __shfl_xor(lt, 8, 32);
      lt += __shfl_xor(lt, 16, 32);
      if (t == 0){
        float rs = __expf(mold - mnew);
        rsS = rs;
        stM = mnew;
        stL = stL*rs + lt;
      }
    }
    __syncthreads();
    // PV: thread owns e = tid; enc tile re-used from LDS
    {
      const float rs = rsS;
      float s0 = 0.f, s1 = 0.f, s2 = 0.f, s3 = 0.f;
      const __bf16* rp = &rm[cur][tid];
      #pragma unroll
      for (int t = 0; t < 32; t += 4){
        s0 += p_s[t  ] * (float)rp[(t  )*RMW];
        s1 += p_s[t+1] * (float)rp[(t+1)*RMW];
        s2 += p_s[t+2] * (float)rp[(t+2)*RMW];
        s3 += p_s[t+3] * (float)rp[(t+3)*RMW];
      }
      cacc = cacc*rs + ((s0+s1)+(s2+s3));
    }
  }

  partC[((size_t)th*128 + b)*512 + tid] = cacc;
  if (tid == 0){
    partML[((size_t)th*128 + b)*2 + 0] = stM;
    partML[((size_t)th*128 + b)*2 + 1] = stL;
  }
}

// ---------------- combine 2 t-halves -> ctxt -> xh[:,512:1024], hc[:,1024:1536] --
__global__ void k_comb(const float* __restrict__ partC, const float* __restrict__ partML,
                       float* __restrict__ xh, float* __restrict__ hc)
{
  const int b = blockIdx.x, e = threadIdx.x;   // 512 threads
  float m0 = partML[b*2 + 0],        l0 = partML[b*2 + 1];
  float m1 = partML[(128 + b)*2 + 0], l1 = partML[(128 + b)*2 + 1];
  float M  = fmaxf(m0, m1);
  float a0 = __expf(m0 - M), a1 = __expf(m1 - M);
  float L  = l0*a0 + l1*a1;
  float inv = 1.f / L;
  float c0 = partC[(size_t)b*512 + e];
  float c1 = partC[(size_t)(128 + b)*512 + e];
  float v = (c0*a0 + c1*a1) * inv;
  xh[(size_t)b*2048 + 512 + e] = v;
  hc[(size_t)b*1536 + 1024 + e] = v;
}

// ---------------- partial GEMM: Cpart[kc][128][N] = A[:,koff:koff+Kloc] @ W^T ------
__global__ __launch_bounds__(256,2) void k_gemm_part(
    const float* __restrict__ A, int lda,
    const float* __restrict__ W1, int ldw1,
    const float* __restrict__ W2, int ldw2, int ksplit,
    float* __restrict__ Cpart, int ldc, int Kloc)
{
  const int jt = blockIdx.x * 32;
  const int kc = blockIdx.y;
  const int koff = kc * Kloc;
  const int tid = threadIdx.x;
  const int w = tid >> 6, lane = tid & 63;
  const int la = lane & 15, g = lane >> 4;

  __shared__ __align__(16) __bf16 A_s[128][40];
  __shared__ __align__(16) __bf16 B_s[32][40];

  f32x4 acc[2][2];
  #pragma unroll
  for (int i = 0; i < 2; ++i)
    #pragma unroll
    for (int j = 0; j < 2; ++j) acc[i][j] = (f32x4){0.f,0.f,0.f,0.f};

  const int ar = tid >> 1, ac = (tid & 1) * 16;
  const int br = tid >> 3, bc = (tid & 7) * 4;

  for (int kl = 0; kl < Kloc; kl += 32){
    const int kk = koff + kl;
    {
      const float* p = A + (size_t)ar*lda + kk + ac;
      float4 v0 = *(const float4*)(p);
      float4 v1 = *(const float4*)(p+4);
      float4 v2 = *(const float4*)(p+8);
      float4 v3 = *(const float4*)(p+12);
      *(bf16x8*)&A_s[ar][ac]   = cvt8(v0,v1);
      *(bf16x8*)&A_s[ar][ac+8] = cvt8(v2,v3);
    }
    {
      const float* wp = (kk < ksplit)
          ? (W1 + (size_t)(jt+br)*ldw1 + kk + bc)
          : (W2 + (size_t)(jt+br)*ldw2 + (kk - ksplit) + bc);
      float4 v = *(const float4*)wp;
      bf16x4 bv;
      bv[0]=(__bf16)v.x; bv[1]=(__bf16)v.y; bv[2]=(__bf16)v.z; bv[3]=(__bf16)v.w;
      *(bf16x4*)&B_s[br][bc] = bv;
    }
    __syncthreads();
    bf16x8 a0 = *(const bf16x8*)&A_s[w*32 + la][g*8];
    bf16x8 a1 = *(const bf16x8*)&A_s[w*32 + 16 + la][g*8];
    bf16x8 b0 = *(const bf16x8*)&B_s[la][g*8];
    bf16x8 b1 = *(const bf16x8*)&B_s[16 + la][g*8];
    acc[0][0] = __builtin_amdgcn_mfma_f32_16x16x32_bf16(a0, b0, acc[0][0], 0,0,0);
    acc[0][1] = __builtin_amdgcn_mfma_f32_16x16x32_bf16(a0, b1, acc[0][1], 0,0,0);
    acc[1][0] = __builtin_amdgcn_mfma_f32_16x16x32_bf16(a1, b0, acc[1][0], 0,0,0);
    acc[1][1] = __builtin_amdgcn_mfma_f32_16x16x32_bf16(a1, b1, acc[1][1], 0,0,0);
    __syncthreads();
  }

  float* cp = Cpart + (size_t)kc*128*ldc;
  #pragma unroll
  for (int mfi = 0; mfi < 2; ++mfi)
    #pragma unroll
    for (int nf = 0; nf < 2; ++nf)
      #pragma unroll
      for (int r = 0; r < 4; ++r){
        int m = w*32 + mfi*16 + g*4 + r;
        int j = jt + nf*16 + la;
        cp[(size_t)m*ldc + j] = acc[mfi][nf][r];
      }
}

// ---------------- LSTM finisher: sum 4 partials + biases + pointwise ----------------
__global__ void k_lstm_fin(const float* __restrict__ partG, const float* __restrict__ b_ih,
                           const float* __restrict__ b_hh, const float* __restrict__ c0,
                           float* __restrict__ out, float* __restrict__ hc)
{
  const int idx = blockIdx.x*256 + threadIdx.x;   // 0..131071
  const int b = idx >> 10, h = idx & 1023;
  float gi = b_ih[h]        + b_hh[h];
  float gf = b_ih[1024 + h] + b_hh[1024 + h];
  float gg = b_ih[2048 + h] + b_hh[2048 + h];
  float go = b_ih[3072 + h] + b_hh[3072 + h];
  #pragma unroll
  for (int kc = 0; kc < 4; ++kc){
    const float* gp = partG + ((size_t)kc*128 + b)*4096;
    gi += gp[h]; gf += gp[1024 + h]; gg += gp[2048 + h]; go += gp[3072 + h];
  }
  float c1 = sigf(gf)*c0[idx] + sigf(gi)*tanh_f(gg);
  float h1 = sigf(go)*tanh_f(c1);
  out[131072 + idx] = h1;
  out[262144 + idx] = c1;
  hc[(size_t)b*1536 + h] = h1;
}

// ---------------- proj finisher: sum 4 partials + bias + tanh -> out[:131072] ------
__global__ void k_proj_fin(const float* __restrict__ partP, const float* __restrict__ b_proj,
                           float* __restrict__ out)
{
  const int idx = blockIdx.x*256 + threadIdx.x;   // 0..131071
  const int b = idx >> 10, j = idx & 1023;
  float s = b_proj[j];
  #pragma unroll
  for (int kc = 0; kc < 4; ++kc)
    s += partP[((size_t)kc*128 + b)*1024 + j];
  out[idx] = tanh_f(s);
}

extern "C" void kernel_launch(void* const* d_in, const int* in_sizes, int n_in,
                              void* d_out, int out_size, void* d_ws, size_t ws_size,
                              hipStream_t stream)
{
  const float* embed  = (const float*)d_in[0];
  const float* h0     = (const float*)d_in[1];
  const float* c0     = (const float*)d_in[2];
  const float* enc    = (const float*)d_in[3];
  const float* W_ph   = (const float*)d_in[4];
  const float* W_pe   = (const float*)d_in[5];
  const float* w_fc2  = (const float*)d_in[6];
  const float* W_ih   = (const float*)d_in[7];
  const float* W_hh   = (const float*)d_in[8];
  const float* b_ih   = (const float*)d_in[9];
  const float* b_hh   = (const float*)d_in[10];
  const float* W_proj = (const float*)d_in[11];
  const float* b_proj = (const float*)d_in[12];
  const unsigned char* mask = (const unsigned char*)d_in[13];

  float* ws     = (float*)d_ws;
  float* ph     = ws;                   //   32768
  float* xh     = ws + 32768;           //  262144 (128x2048: [embed|ctxt|h])
  float* hc     = ws + 294912;          //  196608 (128x1536: [h1|ctxt])
  float* partC  = ws + 491520;          //  131072 (2 x 128 x 512)
  float* partML = ws + 622592;          //     512 (2 x 128 x 2)
  float* partG  = ws + 623104;          // 2097152 (4 x 128 x 4096)
  float* partP  = ws + 2720256;         //  524288 (4 x 128 x 1024)
  __bf16* wpeX  = (__bf16*)(ws + 3244544);   // 131072 bf16 (256 KB)
  float* out    = (float*)d_out;

  k_frag  <<<64, 256, 0, stream>>>(W_pe, wpeX);
  k_ph    <<<128, 256, 0, stream>>>(h0, W_ph, ph);
  k_concat<<<128, 256, 0, stream>>>(embed, h0, xh);
  k_fused <<<dim3(2,128), 512, 0, stream>>>(enc, wpeX, ph, w_fc2, mask,
                                            partC, partML);
  k_comb  <<<128, 512, 0, stream>>>(partC, partML, xh, hc);
  k_gemm_part<<<dim3(128,4), 256, 0, stream>>>(xh, 2048, W_ih, 1024, W_hh, 1024, 1024,
                                               partG, 4096, 512);
  k_lstm_fin<<<512, 256, 0, stream>>>(partG, b_ih, b_hh, c0, out, hc);
  k_gemm_part<<<dim3(32,4), 256, 0, stream>>>(hc, 1536, W_proj, 1536, nullptr, 0, 1536,
                                              partP, 1024, 384);
  k_proj_fin<<<512, 256, 0, stream>>>(partP, b_proj, out);
}